// Round 5
// baseline (421.823 us; speedup 1.0000x reference)
//
#include <hip/hip_runtime.h>

#define IN   128
#define HID  16
#define OUT  64
#define BK   64      // nodes per bucket (bucket = dst >> 6)

// ---- Kernel A: fused  proj1 (blocks [0, nproj))  ||  coarse histogram (rest)
// proj: xs[i] = x[i]@Ws1 ; xn[i] = x[i]@Wn1   (R4-proven structure, 8 nodes/blk)
// hist: per-block LDS histogram of dst>>6, merged with global atomics.
__global__ void k_proj_hist(const float* __restrict__ x,
                            const float* __restrict__ Ws,
                            const float* __restrict__ Wn,
                            const int* __restrict__ dst,
                            float* __restrict__ xs,
                            float* __restrict__ xn,
                            int* __restrict__ bhist,
                            int n, int e, int nproj, int K) {
    __shared__ float smem[IN * 32 + 8 * IN];   // 20 KB, overlaid per role
    int tid = threadIdx.x;   // 256
    if ((int)blockIdx.x < nproj) {
        float (*lw)[32] = (float (*)[32])smem;
        float (*lx)[IN] = (float (*)[IN])(smem + IN * 32);
        for (int i = tid; i < IN * 32; i += 256) {
            int k = i >> 5, j = i & 31;
            lw[k][j] = (j < HID) ? Ws[k * HID + j] : Wn[k * HID + (j - 16)];
        }
        int node0 = blockIdx.x * 8;
        for (int i = tid; i < 8 * IN; i += 256) {
            int r = i >> 7, c = i & 127;
            int node = node0 + r;
            lx[r][c] = (node < n) ? x[(size_t)node * IN + c] : 0.f;
        }
        __syncthreads();
        int r = tid >> 5;
        int j = tid & 31;
        int node = node0 + r;
        if (node >= n) return;
        float acc = 0.f;
        #pragma unroll
        for (int k = 0; k < IN; ++k) acc += lx[r][k] * lw[k][j];
        if (j < HID) xs[(size_t)node * HID + j] = acc;
        else         xn[(size_t)node * HID + (j - 16)] = acc;
    } else {
        int* hist = (int*)smem;             // K <= 1024 ints
        for (int i = tid; i < K; i += 256) hist[i] = 0;
        __syncthreads();
        int b = blockIdx.x - nproj;         // each hist block: 4096 edges
        const int4* d4 = (const int4*)dst;
        #pragma unroll
        for (int i = 0; i < 4; ++i) {
            int i4 = b * 1024 + i * 256 + tid;
            int elem = i4 * 4;
            if (elem + 3 < e) {
                int4 v = d4[i4];
                atomicAdd(&hist[v.x >> 6], 1);
                atomicAdd(&hist[v.y >> 6], 1);
                atomicAdd(&hist[v.z >> 6], 1);
                atomicAdd(&hist[v.w >> 6], 1);
            } else {
                for (int j = elem; j < e && j < elem + 4; ++j)
                    atomicAdd(&hist[dst[j] >> 6], 1);
            }
        }
        __syncthreads();
        for (int i = tid; i < K; i += 256) {
            int c = hist[i];
            if (c) atomicAdd(&bhist[i], c);
        }
    }
}

// ---- Kernel B: exclusive scan of K bucket counts (single 1024-thread block)
__global__ void k_bscan(const int* __restrict__ bhist,
                        int* __restrict__ boff,
                        int* __restrict__ cursor, int K, int e) {
    __shared__ int sm[1024];
    int tid = threadIdx.x;   // 1024
    int v = (tid < K) ? bhist[tid] : 0;
    sm[tid] = v;
    __syncthreads();
    for (int off = 1; off < 1024; off <<= 1) {
        int t = (tid >= off) ? sm[tid - off] : 0;
        __syncthreads();
        sm[tid] += t;
        __syncthreads();
    }
    if (tid < K) {
        int excl = sm[tid] - v;
        boff[tid] = excl;
        cursor[tid] = excl;
    }
    if (tid == 0) boff[K] = e;
}

// ---- Kernel C: coarse place. packed = (src<<6) | (dst&63), bucket-clustered.
__global__ void k_place(const int* __restrict__ src, const int* __restrict__ dst,
                        int* __restrict__ cursor,
                        unsigned* __restrict__ bedge, int e) {
    int t = blockIdx.x * blockDim.x + threadIdx.x;
    int elem = t * 4;
    const int4* s4 = (const int4*)src;
    const int4* d4 = (const int4*)dst;
    if (elem + 3 < e) {
        int4 s = s4[t];
        int4 d = d4[t];
        int p0 = atomicAdd(&cursor[d.x >> 6], 1);
        int p1 = atomicAdd(&cursor[d.y >> 6], 1);
        int p2 = atomicAdd(&cursor[d.z >> 6], 1);
        int p3 = atomicAdd(&cursor[d.w >> 6], 1);
        bedge[p0] = ((unsigned)s.x << 6) | (unsigned)(d.x & 63);
        bedge[p1] = ((unsigned)s.y << 6) | (unsigned)(d.y & 63);
        bedge[p2] = ((unsigned)s.z << 6) | (unsigned)(d.z & 63);
        bedge[p3] = ((unsigned)s.w << 6) | (unsigned)(d.w & 63);
    } else {
        for (int i = elem; i < e && i < elem + 4; ++i) {
            int pos = atomicAdd(&cursor[dst[i] >> 6], 1);
            bedge[pos] = ((unsigned)src[i] << 6) | (unsigned)(dst[i] & 63);
        }
    }
}

// ---- Kernel D: layer-1 aggregate per bucket (LDS accumulate) + finish
//      h = relu(xs + sum(xn[src])/deg + b1)
__global__ void __launch_bounds__(512)
k_agg1(const unsigned* __restrict__ bedge, const int* __restrict__ boff,
       const float* __restrict__ xs, const float* __restrict__ xn,
       const float* __restrict__ b1, float* __restrict__ h, int n) {
    __shared__ float acc[BK][HID];   // 4 KB
    __shared__ int   deg[BK];
    int tid = threadIdx.x;   // 512
    int b = blockIdx.x;
    for (int i = tid; i < BK * HID; i += 512) ((float*)acc)[i] = 0.f;
    if (tid < BK) deg[tid] = 0;
    __syncthreads();
    int s0 = boff[b], s1 = boff[b + 1];
    int d = tid & 15;
    int g = tid >> 4;    // 32 edge slots
    int k = s0 + g;
    // 2-deep software pipeline: two independent gather chains
    for (; k + 32 < s1; k += 64) {
        unsigned p0 = bedge[k];
        unsigned p1 = bedge[k + 32];
        float v0 = xn[(size_t)(p0 >> 6) * HID + d];
        float v1 = xn[(size_t)(p1 >> 6) * HID + d];
        atomicAdd(&acc[p0 & 63][d], v0);
        atomicAdd(&acc[p1 & 63][d], v1);
        if (d == 0) { atomicAdd(&deg[p0 & 63], 1); atomicAdd(&deg[p1 & 63], 1); }
    }
    for (; k < s1; k += 32) {
        unsigned p = bedge[k];
        float v = xn[(size_t)(p >> 6) * HID + d];
        atomicAdd(&acc[p & 63][d], v);
        if (d == 0) atomicAdd(&deg[p & 63], 1);
    }
    __syncthreads();
    int node0 = b * BK;
    for (int i = tid; i < BK * HID; i += 512) {
        int dl = i >> 4, dd = i & 15;
        int node = node0 + dl;
        if (node < n) {
            float dg = fmaxf((float)deg[dl], 1.0f);
            float v = xs[(size_t)node * HID + dd] + acc[dl][dd] / dg + b1[dd];
            h[(size_t)node * HID + dd] = fmaxf(v, 0.f);
        }
    }
}

// ---- Kernel E: layer-2 aggregate per bucket + fused output GEMM
//      out = h@Ws2 + (sum(h[src])/deg)@Wn2 + b2
__global__ void __launch_bounds__(512)
k_agg2_out(const unsigned* __restrict__ bedge, const int* __restrict__ boff,
           const float* __restrict__ h,
           const float* __restrict__ Ws2, const float* __restrict__ Wn2,
           const float* __restrict__ b2, float* __restrict__ out, int n) {
    __shared__ float acc[BK][HID];   // 4 KB
    __shared__ float lh[BK][HID];    // 4 KB
    __shared__ float lws[HID][OUT];  // 4 KB
    __shared__ float lwn[HID][OUT];  // 4 KB
    __shared__ float lb2[OUT];
    __shared__ int   deg[BK];
    int tid = threadIdx.x;   // 512
    int b = blockIdx.x;
    int node0 = b * BK;
    for (int i = tid; i < BK * HID; i += 512) {
        ((float*)acc)[i] = 0.f;
        int node = node0 + (i >> 4);
        lh[i >> 4][i & 15] = (node < n) ? h[(size_t)node * HID + (i & 15)] : 0.f;
    }
    for (int i = tid; i < HID * OUT; i += 512) {
        ((float*)lws)[i] = Ws2[i];
        ((float*)lwn)[i] = Wn2[i];
    }
    if (tid < OUT) lb2[tid] = b2[tid];
    if (tid < BK) deg[tid] = 0;
    __syncthreads();
    int s0 = boff[b], s1 = boff[b + 1];
    int d = tid & 15;
    int g = tid >> 4;
    int k = s0 + g;
    for (; k + 32 < s1; k += 64) {
        unsigned p0 = bedge[k];
        unsigned p1 = bedge[k + 32];
        float v0 = h[(size_t)(p0 >> 6) * HID + d];
        float v1 = h[(size_t)(p1 >> 6) * HID + d];
        atomicAdd(&acc[p0 & 63][d], v0);
        atomicAdd(&acc[p1 & 63][d], v1);
        if (d == 0) { atomicAdd(&deg[p0 & 63], 1); atomicAdd(&deg[p1 & 63], 1); }
    }
    for (; k < s1; k += 32) {
        unsigned p = bedge[k];
        float v = h[(size_t)(p >> 6) * HID + d];
        atomicAdd(&acc[p & 63][d], v);
        if (d == 0) atomicAdd(&deg[p & 63], 1);
    }
    __syncthreads();
    for (int i = tid; i < BK * OUT; i += 512) {
        int nl = i >> 6, o = i & 63;
        int node = node0 + nl;
        if (node >= n) continue;
        float inv = 1.0f / fmaxf((float)deg[nl], 1.0f);
        float acm = lb2[o];
        #pragma unroll
        for (int j = 0; j < HID; ++j)
            acm += lh[nl][j] * lws[j][o] + acc[nl][j] * inv * lwn[j][o];
        out[(size_t)node * OUT + o] = acm;
    }
}

extern "C" void kernel_launch(void* const* d_in, const int* in_sizes, int n_in,
                              void* d_out, int out_size, void* d_ws, size_t ws_size,
                              hipStream_t stream) {
    const float* x   = (const float*)d_in[0];
    const int*   src = (const int*)d_in[1];
    const int*   dst = (const int*)d_in[2];
    const float* Ws1 = (const float*)d_in[3];
    const float* Wn1 = (const float*)d_in[4];
    const float* b1  = (const float*)d_in[5];
    const float* Ws2 = (const float*)d_in[6];
    const float* Wn2 = (const float*)d_in[7];
    const float* b2  = (const float*)d_in[8];
    float* out = (float*)d_out;

    int n = in_sizes[0] / IN;    // 50000
    int e = in_sizes[1];         // 800000
    int K = (n + BK - 1) / BK;   // 782 buckets

    // ws: bhist[K] | boff[K+1] | cursor[K] | bedge[e] | xs[n*16] | xn[n*16] | h[n*16]
    int* bhist  = (int*)d_ws;
    int* boff   = bhist + K;
    int* cursor = boff + (K + 1);
    unsigned* bedge = (unsigned*)(cursor + K);
    float* xs = (float*)(bedge + e);
    float* xn = xs + (size_t)n * HID;
    float* h  = xn + (size_t)n * HID;

    hipMemsetAsync(bhist, 0, (size_t)K * sizeof(int), stream);

    int nproj = (n + 7) / 8;                 // 6250
    int nhist = (e + 4095) / 4096;           // 196
    k_proj_hist<<<nproj + nhist, 256, 0, stream>>>(x, Ws1, Wn1, dst, xs, xn,
                                                   bhist, n, e, nproj, K);

    k_bscan<<<1, 1024, 0, stream>>>(bhist, boff, cursor, K, e);

    int pblk = ((e + 3) / 4 + 255) / 256;
    k_place<<<pblk, 256, 0, stream>>>(src, dst, cursor, bedge, e);

    k_agg1<<<K, 512, 0, stream>>>(bedge, boff, xs, xn, b1, h, n);
    k_agg2_out<<<K, 512, 0, stream>>>(bedge, boff, h, Ws2, Wn2, b2, out, n);
}

// Round 6
// 146.757 us; speedup vs baseline: 2.8743x; 2.8743x over previous
//
#include <hip/hip_runtime.h>

#define IN   128
#define HID  16
#define OUT  64
#define BK   64        // nodes per bucket (bucket = dst >> 6)
#define EPB  16384     // edges per partition block
#define CAP  2048      // LDS staging capacity per bucket (mean ~1024, +32 sigma)

// ---- K1: xs[i] = x[i]@Ws1 ; xn[i] = x[i]@Wn1  (R4-proven: 8 nodes/block)
__global__ void k_proj(const float* __restrict__ x,
                       const float* __restrict__ Ws,
                       const float* __restrict__ Wn,
                       float* __restrict__ xs,
                       float* __restrict__ xn, int n) {
    __shared__ float lw[IN][32];
    __shared__ float lx[8][IN];
    int tid = threadIdx.x;  // 256
    for (int i = tid; i < IN * 32; i += 256) {
        int k = i >> 5, j = i & 31;
        lw[k][j] = (j < HID) ? Ws[k * HID + j] : Wn[k * HID + (j - 16)];
    }
    int node0 = blockIdx.x * 8;
    for (int i = tid; i < 8 * IN; i += 256) {
        int r = i >> 7, c = i & 127;
        int node = node0 + r;
        lx[r][c] = (node < n) ? x[(size_t)node * IN + c] : 0.f;
    }
    __syncthreads();
    int r = tid >> 5, j = tid & 31;
    int node = node0 + r;
    if (node >= n) return;
    float acc = 0.f;
    #pragma unroll
    for (int k = 0; k < IN; ++k) acc += lx[r][k] * lw[k][j];
    if (j < HID) xs[(size_t)node * HID + j] = acc;
    else         xn[(size_t)node * HID + (j - 16)] = acc;
}

// ---- K2: per-block LDS histogram of dst>>6 -> histT[bucket*B + blk] (no global atomics)
__global__ void __launch_bounds__(1024)
k_part1(const int* __restrict__ dst, int* __restrict__ histT,
        int e, int K, int B) {
    __shared__ int lh[1024];
    int tid = threadIdx.x, blk = blockIdx.x;
    for (int i = tid; i < K; i += 1024) lh[i] = 0;
    __syncthreads();
    const int4* d4 = (const int4*)dst;
    #pragma unroll
    for (int it = 0; it < EPB / 4096; ++it) {
        int i4 = blk * (EPB / 4) + it * 1024 + tid;
        int elem = i4 * 4;
        if (elem + 3 < e) {
            int4 v = d4[i4];
            atomicAdd(&lh[v.x >> 6], 1);
            atomicAdd(&lh[v.y >> 6], 1);
            atomicAdd(&lh[v.z >> 6], 1);
            atomicAdd(&lh[v.w >> 6], 1);
        } else {
            for (int j = elem; j < e && j < elem + 4; ++j)
                atomicAdd(&lh[dst[j] >> 6], 1);
        }
    }
    __syncthreads();
    for (int b = tid; b < K; b += 1024) histT[b * B + blk] = lh[b];
}

// ---- K3: in-place exclusive scan of histT[T] (bucket-major); emit boff.
__global__ void __launch_bounds__(1024)
k_scan(int* __restrict__ histT, int* __restrict__ boff,
       int T, int B, int K, int e) {
    __shared__ int sm[1024];
    int tid = threadIdx.x;
    int C = (T + 1023) >> 10;
    int i0 = tid * C, i1 = min(i0 + C, T);
    int s = 0;
    for (int i = i0; i < i1; ++i) s += histT[i];
    sm[tid] = s;
    __syncthreads();
    for (int off = 1; off < 1024; off <<= 1) {
        int t = (tid >= off) ? sm[tid - off] : 0;
        __syncthreads();
        sm[tid] += t;
        __syncthreads();
    }
    int run = sm[tid] - s;   // exclusive base for this chunk
    for (int i = i0; i < i1; ++i) {
        int v = histT[i];
        histT[i] = run;
        if (i % B == 0) boff[i / B] = run;
        run += v;
    }
    if (tid == 0) boff[K] = e;
}

// ---- K4: atomic-free scatter: rank via LDS cursors, clustered packed writes.
__global__ void __launch_bounds__(1024)
k_part2(const int* __restrict__ src, const int* __restrict__ dst,
        const int* __restrict__ histT, unsigned* __restrict__ bedge,
        int e, int K, int B) {
    __shared__ int lbase[1024];
    int tid = threadIdx.x, blk = blockIdx.x;
    for (int b = tid; b < K; b += 1024) lbase[b] = histT[b * B + blk];
    __syncthreads();
    const int4* s4 = (const int4*)src;
    const int4* d4 = (const int4*)dst;
    #pragma unroll
    for (int it = 0; it < EPB / 4096; ++it) {
        int i4 = blk * (EPB / 4) + it * 1024 + tid;
        int elem = i4 * 4;
        if (elem + 3 < e) {
            int4 sv = s4[i4];
            int4 dv = d4[i4];
            int p0 = atomicAdd(&lbase[dv.x >> 6], 1);
            int p1 = atomicAdd(&lbase[dv.y >> 6], 1);
            int p2 = atomicAdd(&lbase[dv.z >> 6], 1);
            int p3 = atomicAdd(&lbase[dv.w >> 6], 1);
            bedge[p0] = ((unsigned)sv.x << 6) | (unsigned)(dv.x & 63);
            bedge[p1] = ((unsigned)sv.y << 6) | (unsigned)(dv.y & 63);
            bedge[p2] = ((unsigned)sv.z << 6) | (unsigned)(dv.z & 63);
            bedge[p3] = ((unsigned)sv.w << 6) | (unsigned)(dv.w & 63);
        } else {
            for (int j = elem; j < e && j < elem + 4; ++j) {
                int pos = atomicAdd(&lbase[dst[j] >> 6], 1);
                bedge[pos] = ((unsigned)src[j] << 6) | (unsigned)(dst[j] & 63);
            }
        }
    }
}

// ---- K5: per-bucket fine segmentation + register pull + relu finish.
//      Also emits fine CSR (fsrc, rowptr) for K6.
__global__ void __launch_bounds__(512)
k_agg1(const unsigned* __restrict__ bedge, const int* __restrict__ boff,
       const float* __restrict__ xs, const float* __restrict__ xn,
       const float* __restrict__ b1, float* __restrict__ h,
       int* __restrict__ fsrc, int* __restrict__ rowptr, int n, int K) {
    __shared__ int ltmp[CAP];
    __shared__ int lsrc[CAP];
    __shared__ int lcnt[BK];
    __shared__ int lofs[BK + 1];
    __shared__ int lcur[BK];
    int tid = threadIdx.x, b = blockIdx.x;
    int s0 = boff[b], s1 = boff[b + 1], cnt = s1 - s0;
    bool fits = (cnt <= CAP);
    if (tid < BK) lcnt[tid] = 0;
    __syncthreads();
    if (fits) {
        for (int i = tid; i < cnt; i += 512) {
            int p = (int)bedge[s0 + i];
            ltmp[i] = p;
            atomicAdd(&lcnt[p & 63], 1);
        }
    } else {
        for (int i = tid; i < cnt; i += 512)
            atomicAdd(&lcnt[(int)bedge[s0 + i] & 63], 1);
    }
    __syncthreads();
    if (tid < BK) {               // wave-level inclusive shfl scan of 64 counts
        int v = lcnt[tid];
        #pragma unroll
        for (int off = 1; off < 64; off <<= 1) {
            int t = __shfl_up(v, off);
            if (tid >= off) v += t;
        }
        lofs[tid + 1] = v;
        if (tid == 0) lofs[0] = 0;
        lcur[tid] = lofs[tid];
    }
    __syncthreads();
    if (fits) {
        for (int i = tid; i < cnt; i += 512) {
            int p = ltmp[i];
            int r = atomicAdd(&lcur[p & 63], 1);
            lsrc[r] = p >> 6;
        }
    } else {
        for (int i = tid; i < cnt; i += 512) {
            int p = (int)bedge[s0 + i];
            int r = atomicAdd(&lcur[p & 63], 1);
            fsrc[s0 + r] = p >> 6;
        }
        __threadfence_block();
    }
    __syncthreads();
    if (fits)
        for (int i = tid; i < cnt; i += 512) fsrc[s0 + i] = lsrc[i];
    int node0 = b * BK;
    if (tid < BK) rowptr[node0 + tid] = s0 + lofs[tid];
    if (b == K - 1 && tid == 0) rowptr[node0 + BK] = s1;
    // pull: 32 node-slots x 16 dims, 2 passes
    int d = tid & 15, slot = tid >> 4;
    #pragma unroll
    for (int pass = 0; pass < 2; ++pass) {
        int nl = pass * 32 + slot;
        int node = node0 + nl;
        if (node < n) {
            int t0 = lofs[nl], t1 = lofs[nl + 1];
            float a0 = 0.f, a1 = 0.f;
            int k = t0;
            if (fits) {
                for (; k + 1 < t1; k += 2) {
                    a0 += xn[(size_t)lsrc[k] * HID + d];
                    a1 += xn[(size_t)lsrc[k + 1] * HID + d];
                }
                if (k < t1) a0 += xn[(size_t)lsrc[k] * HID + d];
            } else {
                for (; k < t1; ++k) a0 += xn[(size_t)fsrc[s0 + k] * HID + d];
            }
            float dg = fmaxf((float)(t1 - t0), 1.0f);
            float v = xs[(size_t)node * HID + d] + (a0 + a1) / dg + b1[d];
            h[(size_t)node * HID + d] = fmaxf(v, 0.f);
        }
    }
}

// ---- K6: per-bucket pull of h + fused output GEMM.
__global__ void __launch_bounds__(512)
k_agg2_out(const int* __restrict__ fsrc, const int* __restrict__ rowptr,
           const float* __restrict__ h,
           const float* __restrict__ Ws2, const float* __restrict__ Wn2,
           const float* __restrict__ b2, float* __restrict__ out, int n) {
    __shared__ int   lidx[CAP];
    __shared__ int   lofs[BK + 1];
    __shared__ float lh[BK][HID];
    __shared__ float lagg[BK][HID];
    __shared__ float lws[HID][OUT];
    __shared__ float lwn[HID][OUT];
    __shared__ float lb2v[OUT];
    int tid = threadIdx.x, b = blockIdx.x;
    int node0 = b * BK;
    int s0r = rowptr[node0];
    int s1r = rowptr[node0 + BK];
    int cnt = s1r - s0r;
    bool fits = (cnt <= CAP);
    if (tid <= BK) lofs[tid] = rowptr[node0 + tid] - s0r;
    if (fits)
        for (int i = tid; i < cnt; i += 512) lidx[i] = fsrc[s0r + i];
    for (int i = tid; i < BK * HID; i += 512) {
        int node = node0 + (i >> 4);
        lh[i >> 4][i & 15] = (node < n) ? h[(size_t)node * HID + (i & 15)] : 0.f;
    }
    for (int i = tid; i < HID * OUT; i += 512) {
        ((float*)lws)[i] = Ws2[i];
        ((float*)lwn)[i] = Wn2[i];
    }
    if (tid < OUT) lb2v[tid] = b2[tid];
    __syncthreads();
    int d = tid & 15, slot = tid >> 4;
    #pragma unroll
    for (int pass = 0; pass < 2; ++pass) {
        int nl = pass * 32 + slot;
        int t0 = lofs[nl], t1 = lofs[nl + 1];
        float a0 = 0.f, a1 = 0.f;
        int k = t0;
        if (fits) {
            for (; k + 1 < t1; k += 2) {
                a0 += h[(size_t)lidx[k] * HID + d];
                a1 += h[(size_t)lidx[k + 1] * HID + d];
            }
            if (k < t1) a0 += h[(size_t)lidx[k] * HID + d];
        } else {
            for (; k < t1; ++k) a0 += h[(size_t)fsrc[s0r + k] * HID + d];
        }
        float dg = fmaxf((float)(t1 - t0), 1.0f);
        lagg[nl][d] = (a0 + a1) / dg;
    }
    __syncthreads();
    for (int i = tid; i < BK * OUT; i += 512) {
        int nl = i >> 6, o = i & 63;
        int node = node0 + nl;
        if (node >= n) continue;
        float acm = lb2v[o];
        #pragma unroll
        for (int j = 0; j < HID; ++j)
            acm += lh[nl][j] * lws[j][o] + lagg[nl][j] * lwn[j][o];
        out[(size_t)node * OUT + o] = acm;
    }
}

extern "C" void kernel_launch(void* const* d_in, const int* in_sizes, int n_in,
                              void* d_out, int out_size, void* d_ws, size_t ws_size,
                              hipStream_t stream) {
    const float* x   = (const float*)d_in[0];
    const int*   src = (const int*)d_in[1];
    const int*   dst = (const int*)d_in[2];
    const float* Ws1 = (const float*)d_in[3];
    const float* Wn1 = (const float*)d_in[4];
    const float* b1  = (const float*)d_in[5];
    const float* Ws2 = (const float*)d_in[6];
    const float* Wn2 = (const float*)d_in[7];
    const float* b2  = (const float*)d_in[8];
    float* out = (float*)d_out;

    int n = in_sizes[0] / IN;          // 50000
    int e = in_sizes[1];               // 800000
    int K = (n + BK - 1) / BK;         // 782 buckets
    int B = (e + EPB - 1) / EPB;       // 49 partition blocks
    int T = K * B;                     // histT entries

    // ws: histT[T] | boff[K+1] | rowptr[K*BK+1] | bedge[e] | fsrc[e] | xs | xn | h
    int* histT  = (int*)d_ws;
    int* boff   = histT + T;
    int* rowptr = boff + (K + 1);
    unsigned* bedge = (unsigned*)(rowptr + ((size_t)K * BK + 1));
    int* fsrc = (int*)(bedge + e);
    float* xs = (float*)(fsrc + e);
    float* xn = xs + (size_t)n * HID;
    float* h  = xn + (size_t)n * HID;

    k_proj<<<(n + 7) / 8, 256, 0, stream>>>(x, Ws1, Wn1, xs, xn, n);

    k_part1<<<B, 1024, 0, stream>>>(dst, histT, e, K, B);
    k_scan<<<1, 1024, 0, stream>>>(histT, boff, T, B, K, e);
    k_part2<<<B, 1024, 0, stream>>>(src, dst, histT, bedge, e, K, B);

    k_agg1<<<K, 512, 0, stream>>>(bedge, boff, xs, xn, b1, h, fsrc, rowptr, n, K);
    k_agg2_out<<<K, 512, 0, stream>>>(fsrc, rowptr, h, Ws2, Wn2, b2, out, n);
}

// Round 7
// 108.646 us; speedup vs baseline: 3.8825x; 1.3508x over previous
//
#include <hip/hip_runtime.h>

#define IN   128
#define HID  16
#define OUT  64
#define BK   64        // nodes per bucket (bucket = dst >> 6)
#define EPB  16384     // edges per partition block
#define CAP  2048      // LDS staging capacity per bucket (mean ~1024)

// ---- K1: xs[i] = x[i]@Ws1 ; xn[i] = x[i]@Wn1  (R4-proven: 8 nodes/block)
__global__ void k_proj(const float* __restrict__ x,
                       const float* __restrict__ Ws,
                       const float* __restrict__ Wn,
                       float* __restrict__ xs,
                       float* __restrict__ xn, int n) {
    __shared__ float lw[IN][32];
    __shared__ float lx[8][IN];
    int tid = threadIdx.x;  // 256
    for (int i = tid; i < IN * 32; i += 256) {
        int k = i >> 5, j = i & 31;
        lw[k][j] = (j < HID) ? Ws[k * HID + j] : Wn[k * HID + (j - 16)];
    }
    int node0 = blockIdx.x * 8;
    for (int i = tid; i < 8 * IN; i += 256) {
        int r = i >> 7, c = i & 127;
        int node = node0 + r;
        lx[r][c] = (node < n) ? x[(size_t)node * IN + c] : 0.f;
    }
    __syncthreads();
    int r = tid >> 5, j = tid & 31;
    int node = node0 + r;
    if (node >= n) return;
    float acc = 0.f;
    #pragma unroll
    for (int k = 0; k < IN; ++k) acc += lx[r][k] * lw[k][j];
    if (j < HID) xs[(size_t)node * HID + j] = acc;
    else         xn[(size_t)node * HID + (j - 16)] = acc;
}

// ---- K2: per-block LDS histogram of dst>>6 -> histT[bucket*B + blk]
__global__ void __launch_bounds__(1024)
k_part1(const int* __restrict__ dst, int* __restrict__ histT,
        int e, int K, int B) {
    __shared__ int lh[1024];
    int tid = threadIdx.x, blk = blockIdx.x;
    for (int i = tid; i < K; i += 1024) lh[i] = 0;
    __syncthreads();
    const int4* d4 = (const int4*)dst;
    #pragma unroll
    for (int it = 0; it < EPB / 4096; ++it) {
        int i4 = blk * (EPB / 4) + it * 1024 + tid;
        int elem = i4 * 4;
        if (elem + 3 < e) {
            int4 v = d4[i4];
            atomicAdd(&lh[v.x >> 6], 1);
            atomicAdd(&lh[v.y >> 6], 1);
            atomicAdd(&lh[v.z >> 6], 1);
            atomicAdd(&lh[v.w >> 6], 1);
        } else {
            for (int j = elem; j < e && j < elem + 4; ++j)
                atomicAdd(&lh[dst[j] >> 6], 1);
        }
    }
    __syncthreads();
    for (int b = tid; b < K; b += 1024) histT[b * B + blk] = lh[b];
}

// ---- K3a: per-bucket totals (parallel over buckets, contiguous rows)
__global__ void k_scanA(const int* __restrict__ histT, int* __restrict__ btot,
                        int K, int B) {
    int b = blockIdx.x * blockDim.x + threadIdx.x;
    if (b >= K) return;
    const int* row = histT + (size_t)b * B;
    int s = 0;
    for (int i = 0; i < B; ++i) s += row[i];
    btot[b] = s;
}

// ---- K3b: exclusive scan of K bucket totals (K <= 1024), LDS only
__global__ void __launch_bounds__(1024)
k_scanB(const int* __restrict__ btot, int* __restrict__ boff, int K, int e) {
    __shared__ int sm[1024];
    int tid = threadIdx.x;
    int v = (tid < K) ? btot[tid] : 0;
    sm[tid] = v;
    __syncthreads();
    for (int off = 1; off < 1024; off <<= 1) {
        int t = (tid >= off) ? sm[tid - off] : 0;
        __syncthreads();
        sm[tid] += t;
        __syncthreads();
    }
    if (tid < K) boff[tid] = sm[tid] - v;
    if (tid == 0) boff[K] = e;
}

// ---- K4: scatter; per-(bucket,block) base computed inline from raw histT.
__global__ void __launch_bounds__(1024)
k_part2(const int* __restrict__ src, const int* __restrict__ dst,
        const int* __restrict__ histT, const int* __restrict__ boff,
        unsigned* __restrict__ bedge, int e, int K, int B) {
    __shared__ int lbase[1024];
    int tid = threadIdx.x, blk = blockIdx.x;
    for (int b = tid; b < K; b += 1024) {
        const int* row = histT + (size_t)b * B;
        int s = boff[b];
        for (int i = 0; i < blk; ++i) s += row[i];
        lbase[b] = s;
    }
    __syncthreads();
    const int4* s4 = (const int4*)src;
    const int4* d4 = (const int4*)dst;
    #pragma unroll
    for (int it = 0; it < EPB / 4096; ++it) {
        int i4 = blk * (EPB / 4) + it * 1024 + tid;
        int elem = i4 * 4;
        if (elem + 3 < e) {
            int4 sv = s4[i4];
            int4 dv = d4[i4];
            int p0 = atomicAdd(&lbase[dv.x >> 6], 1);
            int p1 = atomicAdd(&lbase[dv.y >> 6], 1);
            int p2 = atomicAdd(&lbase[dv.z >> 6], 1);
            int p3 = atomicAdd(&lbase[dv.w >> 6], 1);
            bedge[p0] = ((unsigned)sv.x << 6) | (unsigned)(dv.x & 63);
            bedge[p1] = ((unsigned)sv.y << 6) | (unsigned)(dv.y & 63);
            bedge[p2] = ((unsigned)sv.z << 6) | (unsigned)(dv.z & 63);
            bedge[p3] = ((unsigned)sv.w << 6) | (unsigned)(dv.w & 63);
        } else {
            for (int j = elem; j < e && j < elem + 4; ++j) {
                int pos = atomicAdd(&lbase[dst[j] >> 6], 1);
                bedge[pos] = ((unsigned)src[j] << 6) | (unsigned)(dst[j] & 63);
            }
        }
    }
}

// ---- K5: per-bucket fine segmentation + register pull + relu finish.
//      Also emits fine CSR (fsrc, rowptr) for K6.
__global__ void __launch_bounds__(512)
k_agg1(const unsigned* __restrict__ bedge, const int* __restrict__ boff,
       const float* __restrict__ xs, const float* __restrict__ xn,
       const float* __restrict__ b1, float* __restrict__ h,
       int* __restrict__ fsrc, int* __restrict__ rowptr, int n, int K) {
    __shared__ int ltmp[CAP];
    __shared__ int lsrc[CAP];
    __shared__ int lcnt[BK];
    __shared__ int lofs[BK + 1];
    __shared__ int lcur[BK];
    int tid = threadIdx.x, b = blockIdx.x;
    int s0 = boff[b], s1 = boff[b + 1], cnt = s1 - s0;
    bool fits = (cnt <= CAP);
    if (tid < BK) lcnt[tid] = 0;
    __syncthreads();
    if (fits) {
        for (int i = tid; i < cnt; i += 512) {
            int p = (int)bedge[s0 + i];
            ltmp[i] = p;
            atomicAdd(&lcnt[p & 63], 1);
        }
    } else {
        for (int i = tid; i < cnt; i += 512)
            atomicAdd(&lcnt[(int)bedge[s0 + i] & 63], 1);
    }
    __syncthreads();
    if (tid < BK) {               // wave-level inclusive shfl scan of 64 counts
        int v = lcnt[tid];
        #pragma unroll
        for (int off = 1; off < 64; off <<= 1) {
            int t = __shfl_up(v, off);
            if (tid >= off) v += t;
        }
        lofs[tid + 1] = v;
        if (tid == 0) lofs[0] = 0;
        lcur[tid] = lofs[tid];
    }
    __syncthreads();
    if (fits) {
        for (int i = tid; i < cnt; i += 512) {
            int p = ltmp[i];
            int r = atomicAdd(&lcur[p & 63], 1);
            lsrc[r] = p >> 6;
        }
    } else {
        for (int i = tid; i < cnt; i += 512) {
            int p = (int)bedge[s0 + i];
            int r = atomicAdd(&lcur[p & 63], 1);
            fsrc[s0 + r] = p >> 6;
        }
        __threadfence_block();
    }
    __syncthreads();
    if (fits)
        for (int i = tid; i < cnt; i += 512) fsrc[s0 + i] = lsrc[i];
    int node0 = b * BK;
    if (tid < BK) rowptr[node0 + tid] = s0 + lofs[tid];
    if (b == K - 1 && tid == 0) rowptr[node0 + BK] = s1;
    // pull: 32 node-slots x 16 dims, 2 passes
    int d = tid & 15, slot = tid >> 4;
    #pragma unroll
    for (int pass = 0; pass < 2; ++pass) {
        int nl = pass * 32 + slot;
        int node = node0 + nl;
        if (node < n) {
            int t0 = lofs[nl], t1 = lofs[nl + 1];
            float a0 = 0.f, a1 = 0.f;
            int k = t0;
            if (fits) {
                for (; k + 1 < t1; k += 2) {
                    a0 += xn[(size_t)lsrc[k] * HID + d];
                    a1 += xn[(size_t)lsrc[k + 1] * HID + d];
                }
                if (k < t1) a0 += xn[(size_t)lsrc[k] * HID + d];
            } else {
                for (; k < t1; ++k) a0 += xn[(size_t)fsrc[s0 + k] * HID + d];
            }
            float dg = fmaxf((float)(t1 - t0), 1.0f);
            float v = xs[(size_t)node * HID + d] + (a0 + a1) / dg + b1[d];
            h[(size_t)node * HID + d] = fmaxf(v, 0.f);
        }
    }
}

// ---- K6: per-bucket pull of h + fused output GEMM.
__global__ void __launch_bounds__(512)
k_agg2_out(const int* __restrict__ fsrc, const int* __restrict__ rowptr,
           const float* __restrict__ h,
           const float* __restrict__ Ws2, const float* __restrict__ Wn2,
           const float* __restrict__ b2, float* __restrict__ out, int n) {
    __shared__ int   lidx[CAP];
    __shared__ int   lofs[BK + 1];
    __shared__ float lh[BK][HID];
    __shared__ float lagg[BK][HID];
    __shared__ float lws[HID][OUT];
    __shared__ float lwn[HID][OUT];
    __shared__ float lb2v[OUT];
    int tid = threadIdx.x, b = blockIdx.x;
    int node0 = b * BK;
    int s0r = rowptr[node0];
    int s1r = rowptr[node0 + BK];
    int cnt = s1r - s0r;
    bool fits = (cnt <= CAP);
    if (tid <= BK) lofs[tid] = rowptr[node0 + tid] - s0r;
    if (fits)
        for (int i = tid; i < cnt; i += 512) lidx[i] = fsrc[s0r + i];
    for (int i = tid; i < BK * HID; i += 512) {
        int node = node0 + (i >> 4);
        lh[i >> 4][i & 15] = (node < n) ? h[(size_t)node * HID + (i & 15)] : 0.f;
    }
    for (int i = tid; i < HID * OUT; i += 512) {
        ((float*)lws)[i] = Ws2[i];
        ((float*)lwn)[i] = Wn2[i];
    }
    if (tid < OUT) lb2v[tid] = b2[tid];
    __syncthreads();
    int d = tid & 15, slot = tid >> 4;
    #pragma unroll
    for (int pass = 0; pass < 2; ++pass) {
        int nl = pass * 32 + slot;
        int t0 = lofs[nl], t1 = lofs[nl + 1];
        float a0 = 0.f, a1 = 0.f;
        int k = t0;
        if (fits) {
            for (; k + 1 < t1; k += 2) {
                a0 += h[(size_t)lidx[k] * HID + d];
                a1 += h[(size_t)lidx[k + 1] * HID + d];
            }
            if (k < t1) a0 += h[(size_t)lidx[k] * HID + d];
        } else {
            for (; k < t1; ++k) a0 += h[(size_t)fsrc[s0r + k] * HID + d];
        }
        float dg = fmaxf((float)(t1 - t0), 1.0f);
        lagg[nl][d] = (a0 + a1) / dg;
    }
    __syncthreads();
    for (int i = tid; i < BK * OUT; i += 512) {
        int nl = i >> 6, o = i & 63;
        int node = node0 + nl;
        if (node >= n) continue;
        float acm = lb2v[o];
        #pragma unroll
        for (int j = 0; j < HID; ++j)
            acm += lh[nl][j] * lws[j][o] + lagg[nl][j] * lwn[j][o];
        out[(size_t)node * OUT + o] = acm;
    }
}

extern "C" void kernel_launch(void* const* d_in, const int* in_sizes, int n_in,
                              void* d_out, int out_size, void* d_ws, size_t ws_size,
                              hipStream_t stream) {
    const float* x   = (const float*)d_in[0];
    const int*   src = (const int*)d_in[1];
    const int*   dst = (const int*)d_in[2];
    const float* Ws1 = (const float*)d_in[3];
    const float* Wn1 = (const float*)d_in[4];
    const float* b1  = (const float*)d_in[5];
    const float* Ws2 = (const float*)d_in[6];
    const float* Wn2 = (const float*)d_in[7];
    const float* b2  = (const float*)d_in[8];
    float* out = (float*)d_out;

    int n = in_sizes[0] / IN;          // 50000
    int e = in_sizes[1];               // 800000
    int K = (n + BK - 1) / BK;         // 782 buckets
    int B = (e + EPB - 1) / EPB;       // 49 partition blocks
    int T = K * B;                     // histT entries

    // ws: histT[T] | btot[K] | boff[K+1] | rowptr[K*BK+1] | bedge[e] | fsrc[e] | xs | xn | h
    int* histT  = (int*)d_ws;
    int* btot   = histT + T;
    int* boff   = btot + K;
    int* rowptr = boff + (K + 1);
    unsigned* bedge = (unsigned*)(rowptr + ((size_t)K * BK + 1));
    int* fsrc = (int*)(bedge + e);
    float* xs = (float*)(fsrc + e);
    float* xn = xs + (size_t)n * HID;
    float* h  = xn + (size_t)n * HID;

    k_proj<<<(n + 7) / 8, 256, 0, stream>>>(x, Ws1, Wn1, xs, xn, n);

    k_part1<<<B, 1024, 0, stream>>>(dst, histT, e, K, B);
    k_scanA<<<(K + 255) / 256, 256, 0, stream>>>(histT, btot, K, B);
    k_scanB<<<1, 1024, 0, stream>>>(btot, boff, K, e);
    k_part2<<<B, 1024, 0, stream>>>(src, dst, histT, boff, bedge, e, K, B);

    k_agg1<<<K, 512, 0, stream>>>(bedge, boff, xs, xn, b1, h, fsrc, rowptr, n, K);
    k_agg2_out<<<K, 512, 0, stream>>>(fsrc, rowptr, h, Ws2, Wn2, b2, out, n);
}